// Round 10
// baseline (154.272 us; speedup 1.0000x reference)
//
#include <hip/hip_runtime.h>

#define B_N 8192
#define D_N 1024
#define C_N 1024
#define BM 64
#define BN 128
#define BK 64

typedef __attribute__((ext_vector_type(8))) __bf16 bf16x8;
typedef __attribute__((ext_vector_type(4))) __bf16 bf16x4;
typedef __attribute__((ext_vector_type(4))) float floatx4;

__device__ inline unsigned short f2bf(float f) {
  union { float f; unsigned int u; } cv; cv.f = f;
  unsigned int b = cv.u;
  unsigned int r = (b + 0x7FFFu + ((b >> 16) & 1u)) >> 16;  // RNE
  return (unsigned short)r;
}
__device__ inline float d4(const float4 a) {
  return a.x * a.x + a.y * a.y + a.z * a.z + a.w * a.w;
}
__device__ inline ushort4 pk4(const float4 v, const float s) {
  ushort4 u;
  u.x = f2bf(v.x * s); u.y = f2bf(v.y * s);
  u.z = f2bf(v.z * s); u.w = f2bf(v.w * s);
  return u;
}

// ---------------------------------------------------------------------------
// prep_kernel v3: PROTO-ONLY (emb_j untouched — its norms fold into the gemm).
// 1024 blocks, one class each: int4-scan labels for the 8 member rows,
// gather raw fp32 emb_i rows, normalize in-register, mean -> proto bf16 + p2.
// ---------------------------------------------------------------------------
__global__ __launch_bounds__(256) void prep_kernel(
    const float* __restrict__ emb_i, const int* __restrict__ labels,
    unsigned short* __restrict__ proto, float* __restrict__ p2,
    float* __restrict__ out) {
  __shared__ float sx[4][8];
  __shared__ int list[8];
  __shared__ int scnt;

  const int t = threadIdx.x;
  const int lane = t & 63;
  const int wid = t >> 6;
  const int c = blockIdx.x;

  if (t == 0) scnt = 0;
  if (c == 0 && t == 0) out[0] = 0.0f;
  __syncthreads();

  const int4* lab4 = (const int4*)labels;
  for (int i = 0; i < 8; ++i) {
    const int q = i * 256 + t;
    const int4 L = lab4[q];
    const int base = q * 4;
    if (L.x == c) list[atomicAdd(&scnt, 1) & 7] = base;
    if (L.y == c) list[atomicAdd(&scnt, 1) & 7] = base + 1;
    if (L.z == c) list[atomicAdd(&scnt, 1) & 7] = base + 2;
    if (L.w == c) list[atomicAdd(&scnt, 1) & 7] = base + 3;
  }
  __syncthreads();

  const float* base = emb_i + wid * 256;
  float4 v[8];
  float ss[8];
#pragma unroll
  for (int k = 0; k < 8; ++k) {
    v[k] = ((const float4*)(base + (size_t)list[k] * D_N))[lane];
    ss[k] = d4(v[k]);
  }
#pragma unroll
  for (int k = 0; k < 8; ++k)
    for (int o = 32; o; o >>= 1) ss[k] += __shfl_xor(ss[k], o, 64);
  if (lane == 0) {
#pragma unroll
    for (int k = 0; k < 8; ++k) sx[wid][k] = ss[k];
  }
  __syncthreads();

  float4 a = make_float4(0.f, 0.f, 0.f, 0.f);
#pragma unroll
  for (int k = 0; k < 8; ++k) {
    const float tot = sx[0][k] + sx[1][k] + sx[2][k] + sx[3][k];
    const float iv = 1.0f / fmaxf(sqrtf(tot), 1e-12f);
    a.x += v[k].x * iv; a.y += v[k].y * iv;
    a.z += v[k].z * iv; a.w += v[k].w * iv;
  }
  a.x *= 0.125f; a.y *= 0.125f; a.z *= 0.125f; a.w *= 0.125f;

  float pp = d4(a);
  for (int o = 32; o; o >>= 1) pp += __shfl_xor(pp, o, 64);
  __syncthreads();
  if (lane == 0) sx[wid][0] = pp;
  __syncthreads();
  if (t == 0) p2[c] = sx[0][0] + sx[1][0] + sx[2][0] + sx[3][0];

  ((ushort4*)(proto + (size_t)c * D_N + wid * 256))[lane] = pk4(a, 1.0f);
}

// ---------------------------------------------------------------------------
// gemm_loss_kernel v5: 64x128 tile (grid 128x8 = 1024 blocks, ~4-5 blk/CU for
// TLP), BK=64, 16x16x32 bf16 MFMA, XOR-swizzled LDS (conflict-free lineage).
// A staged from RAW fp32 emb_j via VGPR cvt (thread t owns float4-col t&15 of
// rows (t>>4)+16k); row |x|^2 accumulates on the SAME registers across the
// k0 loop -> rn computed in-kernel (16-lane shfl reduce), no prep pass, no
// extra traffic. B (proto bf16, L2-resident) via global_load_lds width=16.
// Epilogue scales dot by rn then fused BCE + per-block atomicAdd.
// ---------------------------------------------------------------------------
__global__ __launch_bounds__(256) void gemm_loss_kernel(
    const float* __restrict__ Ej,            // [B,D] fp32 raw emb_j
    const unsigned short* __restrict__ P,    // [C,D] bf16 prototypes
    const float* __restrict__ p2,            // [C]
    const int* __restrict__ labels,          // [B]
    float* __restrict__ out) {               // scalar (zeroed by prep)
  __shared__ __align__(16) unsigned short As[BM * BK];  // 8 KB
  __shared__ __align__(16) unsigned short Bs[BN * BK];  // 16 KB
  __shared__ float srn[BM];
  __shared__ float sred[4];

  const int t = threadIdx.x;
  const int lane = t & 63;
  const int wid = t >> 6;
  const int wm = (wid >> 1) * 32;   // 2x2 waves; wave tile 32x64
  const int wn = (wid & 1) * 64;
  const int bm = blockIdx.x;
  const int bn = blockIdx.y;

  floatx4 acc[2][4];
#pragma unroll
  for (int i = 0; i < 2; ++i)
#pragma unroll
    for (int j = 0; j < 4; ++j)
      acc[i][j] = (floatx4){0.f, 0.f, 0.f, 0.f};

  // ---- B staging via global_load_lds (XOR swizzle, 4 passes x 32 rows) ----
  const int srow = t >> 3;
  const int scol = (((t & 7) ^ (srow & 7)) << 3);
  const unsigned short* Bg = P + (size_t)(bn * BN + srow) * D_N + scol;
  unsigned short* Bl = Bs + t * 8;

  // ---- A staging via VGPRs: thread t -> rows (t>>4)+16k (k=0..3), f4-col t&15
  const float4* Agp = (const float4*)(Ej + (size_t)(bm * BM + (t >> 4)) * D_N) + (t & 15);
  unsigned short* Aw = As + (t >> 4) * 64 +
                       ((((t & 15) >> 1) ^ ((t >> 4) & 7)) << 3) + (t & 1) * 4;

  float ssr[4] = {0.f, 0.f, 0.f, 0.f};  // row |x|^2 partials (4 rows/thread)

  for (int k0 = 0; k0 < D_N; k0 += BK) {
#pragma unroll
    for (int it = 0; it < 4; ++it) {
      __builtin_amdgcn_global_load_lds(
          (const __attribute__((address_space(1))) void*)(Bg + (size_t)it * 32 * D_N + k0),
          (__attribute__((address_space(3))) void*)(Bl + it * 2048), 16, 0, 0);
    }
    const int kq = k0 >> 2;
#pragma unroll
    for (int k = 0; k < 4; ++k) {
      const float4 w = Agp[k * 4096 + kq];  // 16 rows * 256 float4/row
      ssr[k] += d4(w);
      bf16x4 bv;
      bv[0] = (__bf16)w.x; bv[1] = (__bf16)w.y;
      bv[2] = (__bf16)w.z; bv[3] = (__bf16)w.w;
      *(bf16x4*)(Aw + k * 1024) = bv;  // ds_write_b64
    }
    __syncthreads();
#pragma unroll
    for (int kk = 0; kk < BK; kk += 32) {
      const int swz = ((((kk >> 3) + (lane >> 4)) ^ (lane & 7)) << 3);
      bf16x8 af[2], bfr[4];
#pragma unroll
      for (int mi = 0; mi < 2; ++mi)
        af[mi] = *(const bf16x8*)(As + (wm + mi * 16 + (lane & 15)) * BK + swz);
#pragma unroll
      for (int ni = 0; ni < 4; ++ni)
        bfr[ni] = *(const bf16x8*)(Bs + (wn + ni * 16 + (lane & 15)) * BK + swz);
#pragma unroll
      for (int mi = 0; mi < 2; ++mi)
#pragma unroll
        for (int ni = 0; ni < 4; ++ni)
          acc[mi][ni] = __builtin_amdgcn_mfma_f32_16x16x32_bf16(af[mi], bfr[ni], acc[mi][ni], 0, 0, 0);
    }
    __syncthreads();
  }

  // ---- finalize row inv-norms: reduce across the 16 threads per row ----
#pragma unroll
  for (int k = 0; k < 4; ++k) {
    ssr[k] += __shfl_xor(ssr[k], 1, 64);
    ssr[k] += __shfl_xor(ssr[k], 2, 64);
    ssr[k] += __shfl_xor(ssr[k], 4, 64);
    ssr[k] += __shfl_xor(ssr[k], 8, 64);
  }
  if ((t & 15) == 0) {
#pragma unroll
    for (int k = 0; k < 4; ++k)
      srn[(t >> 4) + 16 * k] = 1.0f / fmaxf(sqrtf(ssr[k]), 1e-12f);
  }
  __syncthreads();

  // ---- epilogue: C/D col=lane&15, row=(lane>>4)*4+reg; dot scaled by rn ----
  const int colb = bn * BN + wn + (lane & 15);
  const int rowloc = wm + ((lane >> 4) << 2);
  float p2c[4];
#pragma unroll
  for (int ni = 0; ni < 4; ++ni) p2c[ni] = p2[colb + ni * 16];

  float lsum = 0.f;
#pragma unroll
  for (int mi = 0; mi < 2; ++mi) {
#pragma unroll
    for (int r = 0; r < 4; ++r) {
      const int rl = rowloc + mi * 16 + r;
      const float rv = srn[rl];
      const int lab = labels[bm * BM + rl];
#pragma unroll
      for (int ni = 0; ni < 4; ++ni) {
        const float dot = acc[mi][ni][r] * rv;
        const float d2 = 1.0f + p2c[ni] - 2.0f * dot;
        const float s = 2.0f - sqrtf(fmaxf(d2, 0.0f));
        const float sp = fmaxf(s, 0.0f) + log1pf(expf(-fabsf(s)));
        lsum += sp - ((lab == colb + ni * 16) ? s : 0.0f);
      }
    }
  }
  for (int o = 32; o; o >>= 1) lsum += __shfl_xor(lsum, o, 64);
  if (lane == 0) sred[wid] = lsum;
  __syncthreads();
  if (t == 0)
    atomicAdd(out, (sred[0] + sred[1] + sred[2] + sred[3]) *
                       (1.0f / ((float)B_N * (float)C_N)));
}

// ---------------------------------------------------------------------------
extern "C" void kernel_launch(void* const* d_in, const int* in_sizes, int n_in,
                              void* d_out, int out_size, void* d_ws, size_t ws_size,
                              hipStream_t stream) {
  const float* emb_i = (const float*)d_in[0];
  const float* emb_j = (const float*)d_in[1];
  const int* labels = (const int*)d_in[2];
  float* out = (float*)d_out;

  char* ws = (char*)d_ws;
  unsigned short* proto = (unsigned short*)ws;                       // 2 MB
  float* p2 = (float*)(ws + (size_t)2097152);                        // 4 KB

  prep_kernel<<<dim3(C_N), 256, 0, stream>>>(emb_i, labels, proto, p2, out);
  gemm_loss_kernel<<<dim3(B_N / BM, C_N / BN), 256, 0, stream>>>(emb_j, proto,
                                                                 p2, labels, out);
}